// Round 4
// baseline (954.540 us; speedup 1.0000x reference)
//
#include <hip/hip_runtime.h>
#include <cstdint>
#include <cstddef>

#define T_STEPS 512
#define BATCH 512
#define F 128
#define ROWS 16
#define NBT (BATCH / ROWS)     // 32 batch tiles
#define BLOCK 512              // 8 waves
#define FP (F + 8)             // fp16 LDS row stride (conflict-spread)
#define FPF (F + 4)
#define TT 16                  // t-steps per producer block
#define L2E 1.4426950408889634f

typedef __attribute__((ext_vector_type(8))) _Float16 half8;
typedef __attribute__((ext_vector_type(4))) _Float16 half4;
typedef __attribute__((ext_vector_type(2))) __fp16   pkh2;   // cvt_pkrtz result type
typedef __attribute__((ext_vector_type(4))) float    f32x4;

__device__ __forceinline__ float frcp_(float x)  { return __builtin_amdgcn_rcpf(x); }
__device__ __forceinline__ float fexp2_(float x) { return __builtin_amdgcn_exp2f(x); }

// ============================================================================
// Producer: xp[t][bt][g] = fp16( scale_g * (x_tile @ Wx_g + b_g) ),
// scale_g = L2E for sigmoid gates (i,f,o), 2*L2E for the tanh gate (g).
// Stored [col128][row16] so the scan's per-lane load is one contiguous 8B.
// ============================================================================
__global__ __launch_bounds__(BLOCK, 2)
void xproj_gemm(const float* __restrict__ x,
                const float* __restrict__ wx0, const float* __restrict__ b0,
                const float* __restrict__ wx1, const float* __restrict__ b1,
                const float* __restrict__ wx2, const float* __restrict__ b2,
                const float* __restrict__ wx3, const float* __restrict__ b3,
                _Float16* __restrict__ xp)
{
    const int tid  = threadIdx.x;
    const int w    = tid >> 6;
    const int lane = tid & 63;
    const int quad = lane >> 4;
    const int l16  = lane & 15;
    const int bt   = blockIdx.x & (NBT - 1);
    const int tc   = blockIdx.x >> 5;          // NBT == 32
    const int row0 = bt * ROWS;
    const int ncol = w * 16 + l16;

    const float* wxp[4] = {wx0, wx1, wx2, wx3};
    const float* bpp[4] = {b0, b1, b2, b3};
    const float scl[4]  = {L2E, L2E, 2.f * L2E, L2E};

    // B-fragments for all 4 gates (pre-scaled): B[k=kc*32+quad*8+j][n=ncol]
    half8 bfr[4][4];
    float bias_v[4];
    #pragma unroll
    for (int g = 0; g < 4; ++g) {
        bias_v[g] = bpp[g][ncol] * scl[g];
        #pragma unroll
        for (int kc = 0; kc < 4; ++kc) {
            half8 v;
            #pragma unroll
            for (int j = 0; j < 4; ++j) {
                const int k = kc * 32 + quad * 8 + 2 * j;
                pkh2 p = __builtin_amdgcn_cvt_pkrtz(wxp[g][k * F + ncol] * scl[g],
                                                    wxp[g][(k + 1) * F + ncol] * scl[g]);
                v[2 * j]     = (_Float16)p[0];
                v[2 * j + 1] = (_Float16)p[1];
            }
            bfr[g][kc] = v;
        }
    }

    for (int tl = 0; tl < TT; ++tl) {
        const int t = tc * TT + tl;
        // A-fragment: A[m=l16][k=kc*32+quad*8+j]
        half8 afr[4];
        #pragma unroll
        for (int kc = 0; kc < 4; ++kc) {
            const float* px = &x[(size_t)(row0 + l16) * (T_STEPS * F)
                                 + (size_t)t * F + kc * 32 + quad * 8];
            const f32x4 u0 = *(const f32x4*)px;
            const f32x4 u1 = *(const f32x4*)(px + 4);
            half8 v;
            #pragma unroll
            for (int j = 0; j < 2; ++j) {
                pkh2 p0 = __builtin_amdgcn_cvt_pkrtz(u0[2 * j], u0[2 * j + 1]);
                pkh2 p1 = __builtin_amdgcn_cvt_pkrtz(u1[2 * j], u1[2 * j + 1]);
                v[2 * j] = (_Float16)p0[0]; v[2 * j + 1] = (_Float16)p0[1];
                v[4 + 2 * j] = (_Float16)p1[0]; v[5 + 2 * j] = (_Float16)p1[1];
            }
            afr[kc] = v;
        }

        f32x4 acc[4];
        #pragma unroll
        for (int g = 0; g < 4; ++g)
            acc[g] = (f32x4){bias_v[g], bias_v[g], bias_v[g], bias_v[g]};
        #pragma unroll
        for (int kc = 0; kc < 4; ++kc) {
            #pragma unroll
            for (int g = 0; g < 4; ++g)
                acc[g] = __builtin_amdgcn_mfma_f32_16x16x32_f16(afr[kc], bfr[g][kc], acc[g], 0, 0, 0);
        }

        #pragma unroll
        for (int g = 0; g < 4; ++g) {
            pkh2 p0 = __builtin_amdgcn_cvt_pkrtz(acc[g][0], acc[g][1]);
            pkh2 p1 = __builtin_amdgcn_cvt_pkrtz(acc[g][2], acc[g][3]);
            half4 hv;
            hv[0] = (_Float16)p0[0]; hv[1] = (_Float16)p0[1];
            hv[2] = (_Float16)p1[0]; hv[3] = (_Float16)p1[1];
            const size_t off = ((((size_t)t * NBT + bt) * 4 + g) * (size_t)(F * ROWS))
                               + (size_t)ncol * ROWS + quad * 4;
            *(half4*)&xp[off] = hv;
        }
    }
}

// ============================================================================
// Scan: 32 blocks (one per batch tile). Wave owns 16 cols for ALL 4 gates →
// elementwise in C-fragment registers, h double-buffered in LDS, 1 barrier/step.
// Preactivations arrive pre-scaled by L2E (2*L2E for tanh gate).
// ============================================================================
__global__ __launch_bounds__(BLOCK, 2)
void lstm_scan(const _Float16* __restrict__ xp,
               const float* __restrict__ wh0, const float* __restrict__ wh1,
               const float* __restrict__ wh2, const float* __restrict__ wh3,
               float* __restrict__ out)
{
    __shared__ _Float16 h_lds[2][ROWS * FP];

    const int tid  = threadIdx.x;
    const int w    = tid >> 6;
    const int lane = tid & 63;
    const int quad = lane >> 4;
    const int l16  = lane & 15;
    const int bt   = blockIdx.x;
    const int row0 = bt * ROWS;
    const int ncol = w * 16 + l16;

    const float* whp[4] = {wh0, wh1, wh2, wh3};
    const float scl[4]  = {L2E, L2E, 2.f * L2E, L2E};
    half8 whfr[4][4];
    #pragma unroll
    for (int g = 0; g < 4; ++g) {
        #pragma unroll
        for (int kc = 0; kc < 4; ++kc) {
            half8 v;
            #pragma unroll
            for (int j = 0; j < 4; ++j) {
                const int k = kc * 32 + quad * 8 + 2 * j;
                pkh2 p = __builtin_amdgcn_cvt_pkrtz(whp[g][k * F + ncol] * scl[g],
                                                    whp[g][(k + 1) * F + ncol] * scl[g]);
                v[2 * j]     = (_Float16)p[0];
                v[2 * j + 1] = (_Float16)p[1];
            }
            whfr[g][kc] = v;
        }
    }

    for (int i = tid; i < ROWS * FP; i += BLOCK) h_lds[0][i] = (_Float16)0.f;

    const size_t lane_off = (size_t)ncol * ROWS + quad * 4;
    half4 xbuf[2][4];
    #pragma unroll
    for (int g = 0; g < 4; ++g)
        xbuf[0][g] = *(const half4*)&xp[(((size_t)0 * NBT + bt) * 4 + g) * (F * ROWS) + lane_off];
    #pragma unroll
    for (int g = 0; g < 4; ++g)
        xbuf[1][g] = *(const half4*)&xp[(((size_t)1 * NBT + bt) * 4 + g) * (F * ROWS) + lane_off];

    float c_st[4] = {0.f, 0.f, 0.f, 0.f};
    float h_f[4]  = {0.f, 0.f, 0.f, 0.f};
    __syncthreads();

    #pragma unroll 2
    for (int t = 0; t < T_STEPS; ++t) {
        const int cur = t & 1;

        half8 ah[4];
        #pragma unroll
        for (int kc = 0; kc < 4; ++kc)
            ah[kc] = *(const half8*)&h_lds[cur][l16 * FP + kc * 32 + quad * 8];

        f32x4 acc[4];
        #pragma unroll
        for (int g = 0; g < 4; ++g) {
            #pragma unroll
            for (int r = 0; r < 4; ++r) acc[g][r] = (float)xbuf[cur][g][r];
        }

        if (t + 2 < T_STEPS) {
            #pragma unroll
            for (int g = 0; g < 4; ++g)
                xbuf[cur][g] = *(const half4*)
                    &xp[(((size_t)(t + 2) * NBT + bt) * 4 + g) * (F * ROWS) + lane_off];
        }

        #pragma unroll
        for (int kc = 0; kc < 4; ++kc) {
            #pragma unroll
            for (int g = 0; g < 4; ++g)
                acc[g] = __builtin_amdgcn_mfma_f32_16x16x32_f16(ah[kc], whfr[g][kc], acc[g], 0, 0, 0);
        }

        // elementwise in C-layout registers; z pre-scaled so exp2 args are direct
        #pragma unroll
        for (int r = 0; r < 4; ++r) {
            const float ig = frcp_(1.f + fexp2_(-acc[0][r]));
            const float fg = frcp_(1.f + fexp2_(-acc[1][r]));
            const float gt = 2.f * frcp_(1.f + fexp2_(-acc[2][r])) - 1.f;
            const float ot = frcp_(1.f + fexp2_(-acc[3][r]));
            const float cn = fg * c_st[r] + ig * gt;
            c_st[r] = cn;
            const float th = 2.f * frcp_(1.f + fexp2_(-2.f * L2E * cn)) - 1.f;
            const float hh = ot * th;
            h_f[r] = hh;
            h_lds[cur ^ 1][(quad * 4 + r) * FP + ncol] = (_Float16)hh;
        }
        __syncthreads();
    }

    #pragma unroll
    for (int r = 0; r < 4; ++r)
        out[(size_t)(row0 + quad * 4 + r) * F + ncol] = h_f[r];
}

// ============================================================================
// Fallback (verified round-1 fused kernel) — used only if ws_size is too small.
// ============================================================================
__device__ __forceinline__ float sigmoidf_(float z) { return 1.f / (1.f + __expf(-z)); }
__device__ __forceinline__ float tanhf_(float z)    { return 2.f / (1.f + __expf(-2.f * z)) - 1.f; }

__global__ __launch_bounds__(BLOCK, 2)
void lstm_fused(const float* __restrict__ x,
                const float* __restrict__ wh_i, const float* __restrict__ wx_i, const float* __restrict__ b_i,
                const float* __restrict__ wh_f, const float* __restrict__ wx_f, const float* __restrict__ b_f,
                const float* __restrict__ wh_g, const float* __restrict__ wx_g, const float* __restrict__ b_g,
                const float* __restrict__ wh_o, const float* __restrict__ wx_o, const float* __restrict__ b_o,
                float* __restrict__ out)
{
    __shared__ _Float16 h_lds[ROWS * FP];
    __shared__ _Float16 x_lds[2][ROWS * FP];
    __shared__ float    pre_lds[4][ROWS * FPF];

    const int tid  = threadIdx.x;
    const int wave = tid >> 6;
    const int lane = tid & 63;
    const int quad = lane >> 4;
    const int l16  = lane & 15;
    const int gate = wave & 3;
    const int nh   = wave >> 2;
    const int row0 = blockIdx.x * ROWS;

    const float* whp = (gate == 0) ? wh_i : (gate == 1) ? wh_f : (gate == 2) ? wh_g : wh_o;
    const float* wxp = (gate == 0) ? wx_i : (gate == 1) ? wx_f : (gate == 2) ? wx_g : wx_o;
    const float* bp  = (gate == 0) ? b_i  : (gate == 1) ? b_f  : (gate == 2) ? b_g  : b_o;

    half8 whfr[4][4], wxfr[4][4];
    float bias_v[4];
    #pragma unroll
    for (int nt = 0; nt < 4; ++nt) {
        const int ncol = nh * 64 + nt * 16 + l16;
        bias_v[nt] = bp[ncol];
        #pragma unroll
        for (int kc = 0; kc < 4; ++kc) {
            half8 a, b;
            #pragma unroll
            for (int j = 0; j < 8; ++j) {
                const int k = kc * 32 + quad * 8 + j;
                a[j] = (_Float16)whp[k * F + ncol];
                b[j] = (_Float16)wxp[k * F + ncol];
            }
            whfr[kc][nt] = a;
            wxfr[kc][nt] = b;
        }
    }

    int erow[4], efeat[4];
    float c_st[4] = {0.f, 0.f, 0.f, 0.f};
    float h_out[4] = {0.f, 0.f, 0.f, 0.f};
    #pragma unroll
    for (int i = 0; i < 4; ++i) {
        const int p = tid + i * BLOCK;
        erow[i]  = p >> 7;
        efeat[i] = p & 127;
    }

    #pragma unroll
    for (int i = 0; i < 4; ++i) {
        h_lds[erow[i] * FP + efeat[i]] = (_Float16)0.f;
        x_lds[0][erow[i] * FP + efeat[i]] =
            (_Float16)x[(size_t)(row0 + erow[i]) * (T_STEPS * F) + efeat[i]];
    }
    __syncthreads();

    for (int t = 0; t < T_STEPS; ++t) {
        const int buf = t & 1;
        half8 ah[4], ax[4];
        #pragma unroll
        for (int kc = 0; kc < 4; ++kc) {
            ah[kc] = *(const half8*)&h_lds[l16 * FP + kc * 32 + quad * 8];
            ax[kc] = *(const half8*)&x_lds[buf][l16 * FP + kc * 32 + quad * 8];
        }
        float xn[4];
        if (t + 1 < T_STEPS) {
            #pragma unroll
            for (int i = 0; i < 4; ++i)
                xn[i] = x[(size_t)(row0 + erow[i]) * (T_STEPS * F) + (size_t)(t + 1) * F + efeat[i]];
        }
        f32x4 acc[4];
        #pragma unroll
        for (int nt = 0; nt < 4; ++nt)
            acc[nt] = (f32x4){bias_v[nt], bias_v[nt], bias_v[nt], bias_v[nt]};
        #pragma unroll
        for (int kc = 0; kc < 4; ++kc) {
            #pragma unroll
            for (int nt = 0; nt < 4; ++nt)
                acc[nt] = __builtin_amdgcn_mfma_f32_16x16x32_f16(ax[kc], wxfr[kc][nt], acc[nt], 0, 0, 0);
        }
        #pragma unroll
        for (int kc = 0; kc < 4; ++kc) {
            #pragma unroll
            for (int nt = 0; nt < 4; ++nt)
                acc[nt] = __builtin_amdgcn_mfma_f32_16x16x32_f16(ah[kc], whfr[kc][nt], acc[nt], 0, 0, 0);
        }
        #pragma unroll
        for (int nt = 0; nt < 4; ++nt) {
            #pragma unroll
            for (int r = 0; r < 4; ++r)
                pre_lds[gate][(quad * 4 + r) * FPF + nh * 64 + nt * 16 + l16] = acc[nt][r];
        }
        __syncthreads();
        #pragma unroll
        for (int i = 0; i < 4; ++i) {
            const int rf = erow[i] * FPF + efeat[i];
            const float zi = pre_lds[0][rf];
            const float zf = pre_lds[1][rf];
            const float zg = pre_lds[2][rf];
            const float zo = pre_lds[3][rf];
            const float ig = sigmoidf_(zi);
            const float fg = sigmoidf_(zf);
            const float gt = tanhf_(zg);
            const float ot = sigmoidf_(zo);
            c_st[i] = fg * c_st[i] + ig * gt;
            const float hh = ot * tanhf_(c_st[i]);
            h_out[i] = hh;
            h_lds[erow[i] * FP + efeat[i]] = (_Float16)hh;
            if (t + 1 < T_STEPS)
                x_lds[1 - buf][erow[i] * FP + efeat[i]] = (_Float16)xn[i];
        }
        __syncthreads();
    }

    #pragma unroll
    for (int i = 0; i < 4; ++i)
        out[(size_t)(row0 + erow[i]) * F + efeat[i]] = h_out[i];
}

extern "C" void kernel_launch(void* const* d_in, const int* in_sizes, int n_in,
                              void* d_out, int out_size, void* d_ws, size_t ws_size,
                              hipStream_t stream) {
    const float* x   = (const float*)d_in[0];
    const float* whi = (const float*)d_in[1];
    const float* wxi = (const float*)d_in[2];
    const float* bi  = (const float*)d_in[3];
    const float* whf = (const float*)d_in[4];
    const float* wxf = (const float*)d_in[5];
    const float* bf  = (const float*)d_in[6];
    const float* whg = (const float*)d_in[7];
    const float* wxg = (const float*)d_in[8];
    const float* bg  = (const float*)d_in[9];
    const float* who = (const float*)d_in[10];
    const float* wxo = (const float*)d_in[11];
    const float* bo  = (const float*)d_in[12];
    float* out = (float*)d_out;

    const size_t need = (size_t)T_STEPS * NBT * 4 * (F * ROWS) * sizeof(_Float16); // 256 MiB

    if (ws_size >= need) {
        _Float16* xp = (_Float16*)d_ws;
        hipLaunchKernelGGL(xproj_gemm, dim3(NBT * (T_STEPS / TT)), dim3(BLOCK), 0, stream,
                           x, wxi, bi, wxf, bf, wxg, bg, wxo, bo, xp);
        hipLaunchKernelGGL(lstm_scan, dim3(NBT), dim3(BLOCK), 0, stream,
                           xp, whi, whf, whg, who, out);
    } else {
        hipLaunchKernelGGL(lstm_fused, dim3(NBT), dim3(BLOCK), 0, stream,
                           x, whi, wxi, bi, whf, wxf, bf, whg, wxg, bg, who, wxo, bo, out);
    }
}

// Round 5
// 743.618 us; speedup vs baseline: 1.2836x; 1.2836x over previous
//
#include <hip/hip_runtime.h>
#include <cstdint>
#include <cstddef>

#define T_STEPS 512
#define BATCH   512
#define F       128
#define ROWS    16
#define NBT     32                       // batch tiles
#define BLOCK   512                      // 8 waves
#define FP      (F + 8)                  // fp16 LDS row stride
#define TT      16                       // t-steps per chunk/stripe
#define NCHUNK  (T_STEPS / TT)           // 32 stripes
#define NFLAGS  (NCHUNK * NBT)           // 1024
#define L2E     1.4426950408889634f
#define RDY     0x13579BDFu              // != 0xAAAAAAAA poison
#define XP_ELTS ((size_t)T_STEPS * NBT * 4 * F * ROWS)
#define XP_BYTES (XP_ELTS * 2)

typedef __attribute__((ext_vector_type(8))) _Float16 half8;
typedef __attribute__((ext_vector_type(4))) _Float16 half4;
typedef __attribute__((ext_vector_type(2))) __fp16   pkh2;
typedef __attribute__((ext_vector_type(4))) float    f32x4;

__device__ __forceinline__ float frcp_(float x)  { return __builtin_amdgcn_rcpf(x); }
__device__ __forceinline__ float fexp2_(float x) { return __builtin_amdgcn_exp2f(x); }

// agent-coherent 8B load (bypasses potentially-stale local L2 — G16)
__device__ __forceinline__ half4 ld_xp8(const _Float16* p) {
    unsigned long long v = __hip_atomic_load((const unsigned long long*)p,
                                             __ATOMIC_RELAXED, __HIP_MEMORY_SCOPE_AGENT);
    return __builtin_bit_cast(half4, v);
}

__device__ __forceinline__ void wait_flag(const unsigned int* f) {
    if (threadIdx.x == 0) {
        while (__hip_atomic_load(f, __ATOMIC_ACQUIRE, __HIP_MEMORY_SCOPE_AGENT) != RDY)
            __builtin_amdgcn_s_sleep(2);
    }
    __syncthreads();
}

// B-fragments for 4 matrices, pre-scaled by L2E (2*L2E for tanh gate g=2):
// fr[g][kc] holds B[k=kc*32+quad*8+j][ncol]
__device__ __forceinline__ void load_bfrags(const float* const* mats, int quad, int ncol,
                                            half8 fr[4][4]) {
    const float scl[4] = {L2E, L2E, 2.f * L2E, L2E};
    #pragma unroll
    for (int g = 0; g < 4; ++g) {
        #pragma unroll
        for (int kc = 0; kc < 4; ++kc) {
            half8 v;
            #pragma unroll
            for (int j = 0; j < 4; ++j) {
                const int k = kc * 32 + quad * 8 + 2 * j;
                pkh2 p = __builtin_amdgcn_cvt_pkrtz(mats[g][k * F + ncol] * scl[g],
                                                    mats[g][(k + 1) * F + ncol] * scl[g]);
                v[2 * j] = (_Float16)p[0]; v[2 * j + 1] = (_Float16)p[1];
            }
            fr[g][kc] = v;
        }
    }
}

// one 16-step chunk of x-projection for batch tile bt, stripe tc
__device__ __forceinline__ void produce_chunk(const float* __restrict__ x,
                                              const half8 bfr[4][4], const float bias_v[4],
                                              int bt, int tc, int quad, int l16, int ncol,
                                              _Float16* __restrict__ xp) {
    const int row0 = bt * ROWS;
    for (int tl = 0; tl < TT; ++tl) {
        const int t = tc * TT + tl;
        half8 afr[4];
        #pragma unroll
        for (int kc = 0; kc < 4; ++kc) {
            const float* px = &x[(size_t)(row0 + l16) * (T_STEPS * F)
                                 + (size_t)t * F + kc * 32 + quad * 8];
            const f32x4 u0 = *(const f32x4*)px;
            const f32x4 u1 = *(const f32x4*)(px + 4);
            half8 v;
            #pragma unroll
            for (int j = 0; j < 2; ++j) {
                pkh2 p0 = __builtin_amdgcn_cvt_pkrtz(u0[2 * j], u0[2 * j + 1]);
                pkh2 p1 = __builtin_amdgcn_cvt_pkrtz(u1[2 * j], u1[2 * j + 1]);
                v[2 * j] = (_Float16)p0[0]; v[2 * j + 1] = (_Float16)p0[1];
                v[4 + 2 * j] = (_Float16)p1[0]; v[5 + 2 * j] = (_Float16)p1[1];
            }
            afr[kc] = v;
        }
        f32x4 acc[4];
        #pragma unroll
        for (int g = 0; g < 4; ++g)
            acc[g] = (f32x4){bias_v[g], bias_v[g], bias_v[g], bias_v[g]};
        #pragma unroll
        for (int kc = 0; kc < 4; ++kc) {
            #pragma unroll
            for (int g = 0; g < 4; ++g)
                acc[g] = __builtin_amdgcn_mfma_f32_16x16x32_f16(afr[kc], bfr[g][kc], acc[g], 0, 0, 0);
        }
        #pragma unroll
        for (int g = 0; g < 4; ++g) {
            pkh2 p0 = __builtin_amdgcn_cvt_pkrtz(acc[g][0], acc[g][1]);
            pkh2 p1 = __builtin_amdgcn_cvt_pkrtz(acc[g][2], acc[g][3]);
            half4 hv;
            hv[0] = (_Float16)p0[0]; hv[1] = (_Float16)p0[1];
            hv[2] = (_Float16)p1[0]; hv[3] = (_Float16)p1[1];
            const size_t off = ((((size_t)t * NBT + bt) * 4 + g) * (size_t)(F * ROWS))
                               + (size_t)ncol * ROWS + quad * 4;
            *(half4*)&xp[off] = hv;
        }
    }
}

// the sequential LSTM scan over one batch tile; PIPE => flag-gated stripes
template <bool PIPE>
__device__ __forceinline__ void scan_body(const _Float16* __restrict__ xp,
                                          const float* __restrict__ wh0, const float* __restrict__ wh1,
                                          const float* __restrict__ wh2, const float* __restrict__ wh3,
                                          const unsigned int* __restrict__ flags,
                                          float* __restrict__ out,
                                          _Float16 (*h_lds)[ROWS * FP], int bt) {
    const int tid  = threadIdx.x;
    const int w    = tid >> 6;
    const int lane = tid & 63;
    const int quad = lane >> 4;
    const int l16  = lane & 15;
    const int ncol = w * 16 + l16;
    const int row0 = bt * ROWS;

    const float* mats[4] = {wh0, wh1, wh2, wh3};
    half8 whfr[4][4];
    load_bfrags(mats, quad, ncol, whfr);

    for (int i = tid; i < ROWS * FP; i += BLOCK) h_lds[0][i] = (_Float16)0.f;

    if (PIPE) wait_flag(&flags[bt]);   // stripe 0 ready (barrier also covers h_lds init)
    else __syncthreads();

    const size_t lane_off = (size_t)ncol * ROWS + quad * 4;
    half4 xbuf[2][4];
    #pragma unroll
    for (int g = 0; g < 4; ++g)
        xbuf[0][g] = ld_xp8(&xp[(((size_t)0 * NBT + bt) * 4 + g) * (F * ROWS) + lane_off]);
    #pragma unroll
    for (int g = 0; g < 4; ++g)
        xbuf[1][g] = ld_xp8(&xp[(((size_t)1 * NBT + bt) * 4 + g) * (F * ROWS) + lane_off]);

    float c_st[4] = {0.f, 0.f, 0.f, 0.f};
    float h_f[4]  = {0.f, 0.f, 0.f, 0.f};

    for (int tc = 0; tc < NCHUNK; ++tc) {
        // prefetches during this stripe touch t+2 <= 16*tc+17 => need stripe tc+1
        if (PIPE && tc + 1 < NCHUNK) wait_flag(&flags[(tc + 1) * NBT + bt]);
        #pragma unroll 2
        for (int tl = 0; tl < TT; ++tl) {
            const int t = tc * TT + tl;
            const int cur = t & 1;

            half8 ah[4];
            #pragma unroll
            for (int kc = 0; kc < 4; ++kc)
                ah[kc] = *(const half8*)&h_lds[cur][l16 * FP + kc * 32 + quad * 8];

            f32x4 acc[4];
            #pragma unroll
            for (int g = 0; g < 4; ++g) {
                #pragma unroll
                for (int r = 0; r < 4; ++r) acc[g][r] = (float)xbuf[cur][g][r];
            }

            if (t + 2 < T_STEPS) {
                #pragma unroll
                for (int g = 0; g < 4; ++g)
                    xbuf[cur][g] = ld_xp8(
                        &xp[(((size_t)(t + 2) * NBT + bt) * 4 + g) * (F * ROWS) + lane_off]);
            }

            #pragma unroll
            for (int kc = 0; kc < 4; ++kc) {
                #pragma unroll
                for (int g = 0; g < 4; ++g)
                    acc[g] = __builtin_amdgcn_mfma_f32_16x16x32_f16(ah[kc], whfr[g][kc], acc[g], 0, 0, 0);
            }

            // gates: plain 1+exp2 denominators, ONE shared rcp for all four.
            // preacts pre-scaled (L2E; 2*L2E for tanh gate) => |z~| small, no overflow.
            #pragma unroll
            for (int r = 0; r < 4; ++r) {
                const float e1 = fexp2_(-acc[0][r]);
                const float e2 = fexp2_(-acc[1][r]);
                const float e3 = fexp2_(-acc[2][r]);
                const float e4 = fexp2_(-acc[3][r]);
                const float d1 = 1.f + e1, d2 = 1.f + e2, d3 = 1.f + e3, d4 = 1.f + e4;
                const float pa = d1 * d2, pb = d3 * d4;
                const float r0 = frcp_(pa * pb);
                const float ra = r0 * pb, rb = r0 * pa;      // 1/(d1 d2), 1/(d3 d4)
                const float ig = ra * d2;                    // 1/d1
                const float fg = ra * d1;                    // 1/d2
                const float gt = 2.f * (rb * d4) - 1.f;      // tanh = 2/d3 - 1
                const float ot = rb * d3;                    // 1/d4
                const float cn = fg * c_st[r] + ig * gt;
                c_st[r] = cn;
                const float th = 2.f * frcp_(1.f + fexp2_(-2.f * L2E * cn)) - 1.f;
                const float hh = ot * th;
                h_f[r] = hh;
                h_lds[cur ^ 1][(quad * 4 + r) * FP + ncol] = (_Float16)hh;
            }
            __syncthreads();
        }
    }

    #pragma unroll
    for (int r = 0; r < 4; ++r)
        out[(size_t)(row0 + quad * 4 + r) * F + ncol] = h_f[r];
}

// ============================================================================
// Fused pipeline: blocks [0,32) scan, blocks [32,288) produce. Deadlock-free:
// producers wait on nothing; 32 scan blocks can never occupy all 256 CUs.
// ============================================================================
__global__ __launch_bounds__(BLOCK, 4)
void lstm_pipe(const float* __restrict__ x,
               const float* __restrict__ wh0, const float* __restrict__ wx0, const float* __restrict__ b0,
               const float* __restrict__ wh1, const float* __restrict__ wx1, const float* __restrict__ b1,
               const float* __restrict__ wh2, const float* __restrict__ wx2, const float* __restrict__ b2,
               const float* __restrict__ wh3, const float* __restrict__ wx3, const float* __restrict__ b3,
               _Float16* __restrict__ xp, unsigned int* __restrict__ flags,
               float* __restrict__ out)
{
    __shared__ _Float16 h_lds[2][ROWS * FP];

    if (blockIdx.x < NBT) {
        scan_body<true>(xp, wh0, wh1, wh2, wh3, flags, out, h_lds, blockIdx.x);
    } else {
        const int tid  = threadIdx.x;
        const int lane = tid & 63;
        const int quad = lane >> 4;
        const int l16  = lane & 15;
        const int ncol = (tid >> 6) * 16 + l16;
        const int p    = blockIdx.x - NBT;       // 0..255
        const int bt   = p & (NBT - 1);
        const int tc0  = p >> 5;                 // 0..7
        const float* mats[4] = {wx0, wx1, wx2, wx3};
        const float* bp_[4]  = {b0, b1, b2, b3};
        const float scl[4]   = {L2E, L2E, 2.f * L2E, L2E};
        half8 bfr[4][4];
        load_bfrags(mats, quad, ncol, bfr);
        float bias_v[4];
        #pragma unroll
        for (int g = 0; g < 4; ++g) bias_v[g] = bp_[g][ncol] * scl[g];

        // pass i covers stripes 8i..8i+7 across all bt => early stripes finish first
        for (int i = 0; i < 4; ++i) {
            const int tc = tc0 + 8 * i;
            produce_chunk(x, bfr, bias_v, bt, tc, quad, l16, ncol, xp);
            __syncthreads();                     // drains all threads' stores (vmcnt) to L2
            if (threadIdx.x == 0) {
                __threadfence();                 // agent fence: L2 writeback (covers whole L2)
                __hip_atomic_store(&flags[tc * NBT + bt], RDY,
                                   __ATOMIC_RELEASE, __HIP_MEMORY_SCOPE_AGENT);
            }
        }
    }
}

// ============================================================================
// Sequential fallback (if flags don't fit in ws): producer kernel + scan kernel
// ============================================================================
__global__ __launch_bounds__(BLOCK, 4)
void xproj_gemm(const float* __restrict__ x,
                const float* __restrict__ wx0, const float* __restrict__ b0,
                const float* __restrict__ wx1, const float* __restrict__ b1,
                const float* __restrict__ wx2, const float* __restrict__ b2,
                const float* __restrict__ wx3, const float* __restrict__ b3,
                _Float16* __restrict__ xp)
{
    const int tid  = threadIdx.x;
    const int lane = tid & 63;
    const int quad = lane >> 4;
    const int l16  = lane & 15;
    const int ncol = (tid >> 6) * 16 + l16;
    const int bt   = blockIdx.x & (NBT - 1);
    const int tc   = blockIdx.x >> 5;
    const float* mats[4] = {wx0, wx1, wx2, wx3};
    const float* bp_[4]  = {b0, b1, b2, b3};
    const float scl[4]   = {L2E, L2E, 2.f * L2E, L2E};
    half8 bfr[4][4];
    load_bfrags(mats, quad, ncol, bfr);
    float bias_v[4];
    #pragma unroll
    for (int g = 0; g < 4; ++g) bias_v[g] = bp_[g][ncol] * scl[g];
    produce_chunk(x, bfr, bias_v, bt, tc, quad, l16, ncol, xp);
}

__global__ __launch_bounds__(BLOCK, 2)
void lstm_scan_seq(const _Float16* __restrict__ xp,
                   const float* __restrict__ wh0, const float* __restrict__ wh1,
                   const float* __restrict__ wh2, const float* __restrict__ wh3,
                   float* __restrict__ out)
{
    __shared__ _Float16 h_lds[2][ROWS * FP];
    scan_body<false>(xp, wh0, wh1, wh2, wh3, nullptr, out, h_lds, blockIdx.x);
}

extern "C" void kernel_launch(void* const* d_in, const int* in_sizes, int n_in,
                              void* d_out, int out_size, void* d_ws, size_t ws_size,
                              hipStream_t stream) {
    const float* x   = (const float*)d_in[0];
    const float* whi = (const float*)d_in[1];
    const float* wxi = (const float*)d_in[2];
    const float* bi  = (const float*)d_in[3];
    const float* whf = (const float*)d_in[4];
    const float* wxf = (const float*)d_in[5];
    const float* bf  = (const float*)d_in[6];
    const float* whg = (const float*)d_in[7];
    const float* wxg = (const float*)d_in[8];
    const float* bg  = (const float*)d_in[9];
    const float* who = (const float*)d_in[10];
    const float* wxo = (const float*)d_in[11];
    const float* bo  = (const float*)d_in[12];
    float* out = (float*)d_out;

    _Float16* xp = (_Float16*)d_ws;
    const size_t need_pipe = XP_BYTES + NFLAGS * sizeof(unsigned int);

    if (ws_size >= need_pipe) {
        unsigned int* flags = (unsigned int*)((char*)d_ws + XP_BYTES);
        hipLaunchKernelGGL(lstm_pipe, dim3(NBT + 256), dim3(BLOCK), 0, stream,
                           x, whi, wxi, bi, whf, wxf, bf, whg, wxg, bg, who, wxo, bo,
                           xp, flags, out);
    } else {
        hipLaunchKernelGGL(xproj_gemm, dim3(NBT * NCHUNK), dim3(BLOCK), 0, stream,
                           x, wxi, bi, wxf, bf, wxg, bg, wxo, bo, xp);
        hipLaunchKernelGGL(lstm_scan_seq, dim3(NBT), dim3(BLOCK), 0, stream,
                           xp, whi, whf, whg, who, out);
    }
}